// Round 7
// baseline (172.437 us; speedup 1.0000x reference)
//
#include <hip/hip_runtime.h>
#include <math.h>

// Capsule dynamic routing, MI355X. Round 12: route barrier chain 3 -> 1.
// R11 post-mortem: route ~40us vs ~8us static floor -> serialization: 3 full
// barriers (first drains all waves' vmcnt), Pl LDS round-trip, 32-thread
// softmax phase. R12 route:
//   - wave-local staging (wave w DMAs rows 8w..8w+7) + per-wave vmcnt(0) gate
//     (no barrier between stage and ph1) -- mechanics proven in R9.
//   - ph1 thread = (rx=l>>3 row, kq=l&7 k-eighth): full k-reduce via 3
//     shfl_xor in-wave; lane kq==0 does softmax IN-REGISTER, writes Cs only.
//     Pl buffer + 2 barriers deleted.
//   - V staged redundantly by each wave (same bytes, 5 DMA/wave) so Vs is
//     valid right after the per-wave gate.
//   - single __syncthreads before ph2 (ph2 reads all rows + Cs).
//   LDS 22.5KB -> 7 blocks/CU.
// iter0/fold unchanged from R11 (verified). Chain:
// iter0(Sp) -> fold0(V) -> route(Gp) -> fold1(V) -> route(Gp) -> fold2(out).

#define BATCH 64
#define NN    2048
#define KD    128
#define JCAP  10
#define DCAP  16
#define JDIM  160
#define EPSQ  1e-7f
#define NT    64      // tiles of TROW rows ; NT*TROW == NN
#define TROW  32

// ws layout (floats): Gp[64][64][10][128] @0 (Sp[64][64][128] aliases @0) ;
//                     V[64][10][128] @5242880
#define WS_GP 0
#define WS_V  (BATCH * NT * JCAP * KD)

__device__ __forceinline__ void gload16(const float* g, void* l) {
  __builtin_amdgcn_global_load_lds(
      (const __attribute__((address_space(1))) void*)g,
      (__attribute__((address_space(3))) void*)l, 16, 0, 0);
}

// ---- K1: per-tile colsum partials Sp[b][tile][k] ----
__global__ __launch_bounds__(256) void f_iter0(const float* __restrict__ u,
                                               float* __restrict__ Sp) {
  const int b = blockIdx.y, tile = blockIdx.x, t = threadIdx.x;
  __shared__ __align__(16) float4 red[256];
  const int c = t & 31, rg = t >> 5;        // 8 row-groups x 4 rows
  const float* p = u + (((size_t)(b * NN + tile * TROW + rg * 4)) << 7) + (c << 2);
  float4 a = make_float4(0.f, 0.f, 0.f, 0.f);
#pragma unroll
  for (int r = 0; r < 4; ++r) {
    const float4 w4 = *(const float4*)(p + ((size_t)r << 7));
    a.x += w4.x; a.y += w4.y; a.z += w4.z; a.w += w4.w;
  }
  red[t] = a;
  __syncthreads();
  if (t < 32) {
    float4 s4 = red[t];
#pragma unroll
    for (int g = 1; g < 8; ++g) {
      const float4 w4 = red[g * 32 + t];
      s4.x += w4.x; s4.y += w4.y; s4.z += w4.z; s4.w += w4.w;
    }
    *(float4*)&Sp[(size_t)(b * NT + tile) * KD + t * 4] = s4;
  }
}

// ---- K2/K4/K6: block (j,b): fold partials -> o[j] -> {V | squash-out} ----
// pass0: In=Sp (x0.1) ; pass1: In=Gp ; both write V. pass2: In=Gp, write out.
__global__ __launch_bounds__(128) void f_fold(const float* __restrict__ In,
                                              const float* __restrict__ W,
                                              float* __restrict__ Out, int pass) {
  const int j = blockIdx.x, b = blockIdx.y, t = threadIdx.x;
  __shared__ float g_s[KD];
  __shared__ float o_s[DCAP];
  if (pass == 0) {
    const float* p = In + (size_t)b * NT * KD + t;        // Sp[b][tl][t]
    float s = 0.f;
#pragma unroll 8
    for (int tl = 0; tl < NT; ++tl) s += p[(size_t)tl * KD];
    g_s[t] = s * 0.1f;
  } else {
    const float* p = In + ((size_t)(b * NT) * JCAP + j) * KD + t;  // Gp[b][tl][j][t]
    float s = 0.f;
#pragma unroll 8
    for (int tl = 0; tl < NT; ++tl) s += p[(size_t)tl * JCAP * KD];
    g_s[t] = s;
  }
  __syncthreads();
  if (t < DCAP) {
    // o[j][d] = sum_k G[j][k] * W[k][j*16+d]
    float a = 0.f;
#pragma unroll 8
    for (int k = 0; k < KD; ++k) a += g_s[k] * W[k * JDIM + j * DCAP + t];
    o_s[t] = a;
  }
  __syncthreads();
  if (pass < 2) {
    // V[b][j][k] = sum_d W[k][j*16+d] * o[j][d]; thread = k
    const float* wp = W + t * JDIM + j * DCAP;
    float a = 0.f;
#pragma unroll
    for (int d = 0; d < DCAP; ++d) a += wp[d] * o_s[d];
    Out[((size_t)(b * JCAP) + j) * KD + t] = a;
  } else if (t < DCAP) {
    float s2 = 0.f;
#pragma unroll
    for (int d = 0; d < DCAP; ++d) s2 += o_s[d] * o_s[d];
    const float sc = s2 / ((1.f + s2) * sqrtf(s2 + EPSQ));
    Out[(size_t)(b * JCAP + j) * DCAP + t] = o_s[t] * sc;
  }
}

// ---- K3/K5: routing pass: logits -> softmax_j -> G partials (global) ----
__global__ __launch_bounds__(256) void f_route(const float* __restrict__ u,
                                               const float* __restrict__ V,
                                               float* __restrict__ Gp) {
  const int b = blockIdx.y, tile = blockIdx.x, t = threadIdx.x;
  const int w = t >> 6, l = t & 63;
  __shared__ __align__(16) float4 u4[TROW * 32];   // 16 KB, XOR-swizzled
  __shared__ __align__(16) float4 Vs4[JCAP * 32];  // 5 KB, linear
  __shared__ __align__(16) float Cs[JCAP * TROW];  // 1.25 KB

  // (1) wave-local DMA: wave w stages u rows 8w..8w+7 (linear dest,
  //     inverse-swizzled per-lane source: logical col L lands at pos L^(r&7))
  //     + the full V (redundantly per wave -> valid after own vmcnt gate).
  {
    const float* ub = u + (((size_t)(b * NN + tile * TROW)) << 7);
#pragma unroll
    for (int p = 0; p < 4; ++p) {
      const int df = (w << 8) + (p << 6);          // wave-uniform f4 slot base
      const int s = df + l;
      const int r = s >> 5, pos = s & 31;
      const int L = pos ^ (r & 7);
      gload16(ub + (((size_t)r) << 7) + (L << 2), &u4[df]);
    }
    const float* vb = V + (((size_t)(b * JCAP)) << 7);
#pragma unroll
    for (int q = 0; q < 5; ++q)
      gload16(vb + ((q * 64 + l) << 2), &Vs4[q * 64]);
  }
  asm volatile("s_waitcnt vmcnt(0)" ::: "memory");  // own-wave DMAs landed
  __builtin_amdgcn_sched_barrier(0);

  // (2) ph1: logits for OWN rows. rx = l>>3 (row), kq = l&7 (k-eighth).
  //     u reads: swizzled slots; V reads: 8-lane broadcasts, octet = kq.
  //     Full k-reduce in-wave (shfl_xor 1,2,4); lane kq==0 does softmax
  //     in-register and writes Cs[j][r].
  {
    const int rx = l >> 3, kq = l & 7;
    const int r = (w << 3) + rx;
    float4 ur[4];
#pragma unroll
    for (int c = 0; c < 4; ++c) ur[c] = u4[(r << 5) + ((c * 8 + kq) ^ rx)];
    float acc[JCAP];
#pragma unroll
    for (int j = 0; j < JCAP; ++j) acc[j] = 0.f;
#pragma unroll
    for (int c = 0; c < 4; ++c) {
#pragma unroll
      for (int j = 0; j < JCAP; ++j) {
        const float4 vv = Vs4[j * 32 + c * 8 + kq];
        acc[j] += ur[c].x * vv.x + ur[c].y * vv.y + ur[c].z * vv.z + ur[c].w * vv.w;
      }
    }
#pragma unroll
    for (int j = 0; j < JCAP; ++j) {
      acc[j] += __shfl_xor(acc[j], 1, 64);
      acc[j] += __shfl_xor(acc[j], 2, 64);
      acc[j] += __shfl_xor(acc[j], 4, 64);
    }
    if (kq == 0) {
      float m = acc[0];
#pragma unroll
      for (int j = 1; j < JCAP; ++j) m = fmaxf(m, acc[j]);
      float ss = 0.f;
#pragma unroll
      for (int j = 0; j < JCAP; ++j) { acc[j] = __expf(acc[j] - m); ss += acc[j]; }
      const float inv = 1.f / ss;
#pragma unroll
      for (int j = 0; j < JCAP; ++j) Cs[j * TROW + r] = acc[j] * inv;
    }
  }
  __syncthreads();   // Cs + all waves' u4 rows visible

  // (3) ph2: G[j][k] = sum_r c[j][r]*u[r][k]. Wave owns j-subset over ALL
  //     rows; lane = k-pair; swizzle term chalf^ri is compile-time per ri.
  {
    const int j0 = (w < 2) ? 3 * w : 2 * w + 2;     // {0,3,6,8}
    const int jn = (w < 2) ? 3 : 2;                 // {3,3,2,2}
    const int chalf = l >> 1, cin = (l & 1) << 1;   // k = 2*l
    float g0[3], g1[3];
#pragma unroll
    for (int jj = 0; jj < 3; ++jj) { g0[jj] = 0.f; g1[jj] = 0.f; }
#pragma unroll
    for (int o = 0; o < 4; ++o) {                   // row octaves
      float ua[8], uc[8];
#pragma unroll
      for (int ri = 0; ri < 8; ++ri) {
        const int r = o * 8 + ri;
        const float2 uu2 =
            *(const float2*)((const float*)&u4[(r << 5) + (chalf ^ ri)] + cin);
        ua[ri] = uu2.x; uc[ri] = uu2.y;
      }
#pragma unroll
      for (int jj = 0; jj < 3; ++jj) {
        if (jj < jn) {
          const float4 cA = *(const float4*)&Cs[(j0 + jj) * TROW + o * 8];
          const float4 cB = *(const float4*)&Cs[(j0 + jj) * TROW + o * 8 + 4];
          g0[jj] += cA.x * ua[0] + cA.y * ua[1] + cA.z * ua[2] + cA.w * ua[3]
                  + cB.x * ua[4] + cB.y * ua[5] + cB.z * ua[6] + cB.w * ua[7];
          g1[jj] += cA.x * uc[0] + cA.y * uc[1] + cA.z * uc[2] + cA.w * uc[3]
                  + cB.x * uc[4] + cB.y * uc[5] + cB.z * uc[6] + cB.w * uc[7];
        }
      }
    }
    float* gb = Gp + ((size_t)(b * NT + tile)) * JCAP * KD;
#pragma unroll
    for (int jj = 0; jj < 3; ++jj)
      if (jj < jn)
        *(float2*)&gb[(j0 + jj) * KD + 2 * l] = make_float2(g0[jj], g1[jj]);
  }
}

extern "C" void kernel_launch(void* const* d_in, const int* in_sizes, int n_in,
                              void* d_out, int out_size, void* d_ws, size_t ws_size,
                              hipStream_t stream) {
  const float* u = (const float*)d_in[0];   // (64,2048,128) fp32
  const float* W = (const float*)d_in[1];   // (128,160) fp32
  float* out = (float*)d_out;               // (64,10,16) fp32
  float* ws  = (float*)d_ws;

  float* Gp = ws + WS_GP;   // Sp aliases this region (fold0 consumes it first)
  float* V  = ws + WS_V;
  f_iter0 <<<dim3(NT, BATCH), 256, 0, stream>>>(u, Gp);
  f_fold  <<<dim3(JCAP, BATCH), 128, 0, stream>>>(Gp, W, V, 0);
  f_route <<<dim3(NT, BATCH), 256, 0, stream>>>(u, V, Gp);
  f_fold  <<<dim3(JCAP, BATCH), 128, 0, stream>>>(Gp, W, V, 1);
  f_route <<<dim3(NT, BATCH), 256, 0, stream>>>(u, V, Gp);
  f_fold  <<<dim3(JCAP, BATCH), 128, 0, stream>>>(Gp, W, out, 2);
}